// Round 1
// 632.988 us; speedup vs baseline: 1.0724x; 1.0724x over previous
//
#include <hip/hip_runtime.h>
#include <math.h>

#define BATCH   2097152
#define NTILES  (BATCH / 16)
#define GRID    2048
#define BLOCK   256
#define WAVES   (GRID * (BLOCK / 64))
#define NREP    16
#define NSETS   8

typedef __attribute__((ext_vector_type(8))) short short8;   // 8 bf16 = 4 VGPRs (MFMA A/B frag)
typedef __attribute__((ext_vector_type(4))) float f32x4;    // MFMA C/D frag
typedef unsigned short ushort_t;

// K-slot interleave: slot s holds natural channel chan(s) = (s>>1) + 16*(s&1).
// Legal because MFMA sums over all 32 K slots: relabeling K on BOTH A and B frags is identity.
// Consequence: C-layout output pair (col c, col c+16) == storage positions (2c, 2c+1),
// so one v_cvt_pk_bf16_f32 produces the exact u32 the transpose tile / global h wants.
__device__ __forceinline__ int chan_of(int s) { return (s >> 1) + ((s & 1) << 4); }

__device__ __forceinline__ float silu_f(float x) {
    return x * __builtin_amdgcn_rcpf(1.0f + __expf(-x));
}
__device__ __forceinline__ unsigned cvt_pk_bf16(float lo, float hi) {   // RTNE, 1 instr for 2 cvts
    unsigned r;
    asm("v_cvt_pk_bf16_f32 %0, %1, %2" : "=v"(r) : "v"(lo), "v"(hi));
    return r;
}
__device__ __forceinline__ unsigned short f2bf(float f) {   // fp32 -> bf16 RTNE (setup-time only)
    union { float f; unsigned u; } v; v.f = f;
    unsigned r = v.u + 0x7fffu + ((v.u >> 16) & 1u);
    return (unsigned short)(r >> 16);
}
__device__ __forceinline__ float bf2f(unsigned short b) {
    union { unsigned u; float f; } v; v.u = ((unsigned)b) << 16;
    return v.f;
}
__device__ __forceinline__ short8 pack8(const float* f) {   // 8 f32 -> 8 bf16 via 4 cvt_pk
    union { short8 s; unsigned u[4]; } r;
    #pragma unroll
    for (int i = 0; i < 4; ++i) r.u[i] = cvt_pk_bf16(f[2 * i], f[2 * i + 1]);
    return r.s;
}
__device__ __forceinline__ f32x4 mfma16(short8 a, short8 b, f32x4 c) {
    return __builtin_amdgcn_mfma_f32_16x16x32_bf16(a, b, c, 0, 0, 0);
}
// B fragment with chan-permuted K rows: slot k holds W[chan(k)][n]. W row-major [K][ldN].
__device__ __forceinline__ short8 wfrag(const float* W, int ldN, int K, int lane, int half, int N) {
    short8 r;
    const int n = (lane & 15) + 16 * half;
    const int k0 = (lane >> 4) * 8;
    #pragma unroll
    for (int j = 0; j < 8; ++j) {
        const int ck = chan_of(k0 + j);
        const float v = (ck < K && n < N) ? W[ck * ldN + n] : 0.f;
        ((unsigned short*)&r)[j] = f2bf(v);
    }
    return r;
}
// BN folded coefs from replicated fp64 sums: y = A*x + C  (natural channel index)
__device__ __forceinline__ void bn_coef(const double* sIn, const float* g, const float* b,
                                        int c, float* A, float* C) {
    double s = 0, q = 0;
    #pragma unroll
    for (int r = 0; r < NREP; ++r) { s += sIn[r * 64 + c]; q += sIn[r * 64 + 32 + c]; }
    const double inv = 1.0 / (double)BATCH;
    const double mu = s * inv, var = q * inv - mu * mu;
    const float a = (float)(1.0 / sqrt(var + 1e-5)) * g[c];
    *A = a; *C = b[c] - (float)mu * a;
}
// C-layout stats: lane holds natural channels (lane&15) and (lane&15)+16
__device__ __forceinline__ void stats_reduce_c(float sS0, float sQ0, float sS1, float sQ1,
                                               float (*sRed)[64], double* sOut, int tid) {
    const int lane = tid & 63, wid = tid >> 6;
    sS0 += __shfl_down(sS0, 32); sS0 += __shfl_down(sS0, 16);
    sQ0 += __shfl_down(sQ0, 32); sQ0 += __shfl_down(sQ0, 16);
    sS1 += __shfl_down(sS1, 32); sS1 += __shfl_down(sS1, 16);
    sQ1 += __shfl_down(sQ1, 32); sQ1 += __shfl_down(sQ1, 16);
    if (lane < 16) {
        sRed[wid][lane] = sS0; sRed[wid][16 + lane] = sS1;
        sRed[wid][32 + lane] = sQ0; sRed[wid][48 + lane] = sQ1;
    }
    __syncthreads();
    if (tid < 64) {
        const float tot = sRed[0][tid] + sRed[1][tid] + sRed[2][tid] + sRed[3][tid];
        atomicAdd(sOut + tid, (double)tot);
    }
}

// ---- Fold rfft -> complex mix -> irfft into one real 32x32 matrix per layer (+I skip) ----
__global__ void setup_f_kernel(const float* __restrict__ wr, const float* __restrict__ wi,
                               float* __restrict__ Fp)
{
    __shared__ double cs[32], sn[32];
    const int l = blockIdx.x, tid = threadIdx.x;
    if (tid < 32) {
        double a = (2.0 * 3.14159265358979323846 / 32.0) * (double)tid;
        cs[tid] = cos(a); sn[tid] = sin(a);
    }
    __syncthreads();
    const float* wrl = wr + l * 289;
    const float* wil = wi + l * 289;
    for (int p = tid; p < 1024; p += BLOCK) {
        const int d = p >> 5, j = p & 31;
        double acc = 0.0;
        for (int m = 0; m < 17; ++m) {
            double yr = 0.0, yi = 0.0;
            for (int k = 0; k < 17; ++k) {
                const double c = cs[(k * d) & 31], s = sn[(k * d) & 31];
                const double a = (double)wrl[k * 17 + m], b = (double)wil[k * 17 + m];
                yr += c * a + s * b;
                yi += c * b - s * a;
            }
            const double alpha = (m == 0 || m == 16) ? 1.0 : 2.0;
            acc += alpha * (cs[(j * m) & 31] * yr - sn[(j * m) & 31] * yi);
        }
        const double F = acc * (1.0 / 32.0);
        Fp[l * 1024 + d * 32 + j] = (float)(F + ((d == j) ? 1.0 : 0.0));
    }
}

// ---- stem: h = x @ stem_w + stem_b (MFMA, K=10 zero-padded); h stored bf16 interleaved ----
__global__ __launch_bounds__(BLOCK) void stem_kernel(
    const float* __restrict__ x, const float* __restrict__ sw, const float* __restrict__ sb,
    ushort_t* __restrict__ h, double* __restrict__ sOut)
{
    __shared__ ushort_t tile[4][512] __attribute__((aligned(16)));
    __shared__ float sRed[4][64];
    const int tid = threadIdx.x, lane = tid & 63, wid = tid >> 6;
    const int m = lane & 15, q = lane >> 4;
    const short8 B0 = wfrag(sw, 32, 10, lane, 0, 32);
    const short8 B1 = wfrag(sw, 32, 10, lane, 1, 32);
    const float bc0 = sb[m], bc1 = sb[m + 16];
    float sS0 = 0, sQ0 = 0, sS1 = 0, sQ1 = 0;
    ushort_t* myT = tile[wid];
    for (int t = blockIdx.x * (BLOCK / 64) + wid; t < NTILES; t += WAVES) {
        const size_t rb = (size_t)t * 16;
        // slot s = q*8+j holds x[chan(s)]: even j -> channel q*4 + j/2 (if <10), odd j -> ch>=16 -> 0
        float c4[4];
        #pragma unroll
        for (int i2 = 0; i2 < 2; ++i2) {
            const int k = q * 4 + 2 * i2;
            if (k + 1 < 10) {
                const float2 v = *(const float2*)(x + (rb + m) * 10 + k);
                c4[2 * i2] = v.x; c4[2 * i2 + 1] = v.y;
            } else { c4[2 * i2] = 0.f; c4[2 * i2 + 1] = 0.f; }
        }
        float xv[8];
        #pragma unroll
        for (int j = 0; j < 8; ++j) xv[j] = (j & 1) ? 0.f : c4[j >> 1];
        const short8 xa = pack8(xv);
        f32x4 a0 = {bc0, bc0, bc0, bc0}, a1 = {bc1, bc1, bc1, bc1};
        a0 = mfma16(xa, B0, a0);
        a1 = mfma16(xa, B1, a1);
        #pragma unroll
        for (int r = 0; r < 4; ++r) {
            sS0 += a0[r]; sQ0 += a0[r] * a0[r];
            sS1 += a1[r]; sQ1 += a1[r] * a1[r];
        }
        // C-layout -> interleaved A-layout: pair (ch m, ch m+16) is one u32 at position 2m
        __builtin_amdgcn_wave_barrier();
        #pragma unroll
        for (int r = 0; r < 4; ++r)
            *(unsigned*)&myT[(q * 4 + r) * 32 + 2 * m] = cvt_pk_bf16(a0[r], a1[r]);
        __builtin_amdgcn_wave_barrier();
        const short8 hv = *(const short8*)(myT + lane * 8);   // coalesced row-major tile
        *(short8*)(h + rb * 32 + lane * 8) = hv;
        __builtin_amdgcn_wave_barrier();
    }
    stats_reduce_c(sS0, sQ0, sS1, sQ1, sRed, sOut + (size_t)(blockIdx.x & (NREP - 1)) * 64, tid);
}

// ---- P1: stats of r1 = silu(bn1(h)) @ W1 + lb1 ----
__global__ __launch_bounds__(BLOCK) void p1_kernel(
    const ushort_t* __restrict__ h_in, const double* __restrict__ sIn, double* __restrict__ sOut,
    const float* __restrict__ g1, const float* __restrict__ b1,
    const float* __restrict__ w1, const float* __restrict__ lb1)
{
    __shared__ float cA[32], cC[32];
    __shared__ float sRed[4][64];
    const int tid = threadIdx.x, lane = tid & 63, wid = tid >> 6;
    if (tid < 32) bn_coef(sIn, g1, b1, tid, &cA[tid], &cC[tid]);
    __syncthreads();
    const int m = lane & 15, q = lane >> 4;
    float a1k[8], c1k[8];
    #pragma unroll
    for (int j = 0; j < 8; ++j) {
        const int c = chan_of(q * 8 + j);
        a1k[j] = cA[c]; c1k[j] = cC[c];
    }
    const short8 W10 = wfrag(w1, 32, 32, lane, 0, 32);
    const short8 W11 = wfrag(w1, 32, 32, lane, 1, 32);
    const float lbc0 = lb1[m], lbc1 = lb1[m + 16];
    float sS0 = 0, sQ0 = 0, sS1 = 0, sQ1 = 0;
    for (int t = blockIdx.x * (BLOCK / 64) + wid; t < NTILES; t += WAVES) {
        const size_t rb = (size_t)t * 16;
        const short8 ha = *(const short8*)(h_in + (rb + m) * 32 + q * 8);
        float tf[8];
        #pragma unroll
        for (int j = 0; j < 8; ++j)
            tf[j] = silu_f(a1k[j] * bf2f(((const unsigned short*)&ha)[j]) + c1k[j]);
        const short8 ta = pack8(tf);
        f32x4 r0 = {lbc0, lbc0, lbc0, lbc0}, r1 = {lbc1, lbc1, lbc1, lbc1};
        r0 = mfma16(ta, W10, r0);
        r1 = mfma16(ta, W11, r1);
        #pragma unroll
        for (int r = 0; r < 4; ++r) {
            sS0 += r0[r]; sQ0 += r0[r] * r0[r];
            sS1 += r1[r]; sQ1 += r1[r] * r1[r];
        }
    }
    stats_reduce_c(sS0, sQ0, sS1, sQ1, sRed, sOut + (size_t)(blockIdx.x & (NREP - 1)) * 64, tid);
}

// ---- P2: h_new = silu(h@Fp + silu(bn2(t@W1+lb1))@W2 + lb2); stats(h_new) or head ----
template<bool LAST>
__global__ __launch_bounds__(BLOCK) void p2_kernel(
    const ushort_t* __restrict__ h_in, ushort_t* __restrict__ h_out, float* __restrict__ out,
    const double* __restrict__ sIn1, const double* __restrict__ sIn2, double* __restrict__ sOut,
    const float* __restrict__ g1, const float* __restrict__ b1,
    const float* __restrict__ w1, const float* __restrict__ lb1,
    const float* __restrict__ g2, const float* __restrict__ b2,
    const float* __restrict__ w2, const float* __restrict__ lb2,
    const float* __restrict__ Fp, const float* __restrict__ hw, const float* __restrict__ hb)
{
    __shared__ float cA1[32], cC1[32], cA2[32], cD2[32];
    __shared__ ushort_t tile[4][512] __attribute__((aligned(16)));
    __shared__ float sRed[4][64];
    const int tid = threadIdx.x, lane = tid & 63, wid = tid >> 6;
    if (tid < 32) {
        bn_coef(sIn1, g1, b1, tid, &cA1[tid], &cC1[tid]);
    } else if (tid < 64) {
        const int c = tid - 32;
        float A, C;
        bn_coef(sIn2, g2, b2, c, &A, &C);
        cA2[c] = A; cD2[c] = C + A * lb1[c];   // fold lb1 into bn2 offset
    }
    __syncthreads();
    const int m = lane & 15, q = lane >> 4;
    float a1k[8], c1k[8];
    #pragma unroll
    for (int j = 0; j < 8; ++j) {
        const int c = chan_of(q * 8 + j);
        a1k[j] = cA1[c]; c1k[j] = cC1[c];
    }
    const float a2c0 = cA2[m], d2c0 = cD2[m], a2c1 = cA2[m + 16], d2c1 = cD2[m + 16];
    const float b2c0 = lb2[m], b2c1 = lb2[m + 16];
    const short8 W10 = wfrag(w1, 32, 32, lane, 0, 32);
    const short8 W11 = wfrag(w1, 32, 32, lane, 1, 32);
    const short8 W20 = wfrag(w2, 32, 32, lane, 0, 32);
    const short8 W21 = wfrag(w2, 32, 32, lane, 1, 32);
    const short8 F0  = wfrag(Fp, 32, 32, lane, 0, 32);
    const short8 F1  = wfrag(Fp, 32, 32, lane, 1, 32);
    short8 HW = {};
    float hbc = 0.f;
    if (LAST) { HW = wfrag(hw, 10, 32, lane, 0, 10); hbc = (m < 10) ? hb[m] : 0.f; }
    float sS0 = 0, sQ0 = 0, sS1 = 0, sQ1 = 0;
    ushort_t* myT = tile[wid];

    for (int t = blockIdx.x * (BLOCK / 64) + wid; t < NTILES; t += WAVES) {
        const size_t rb = (size_t)t * 16;
        const short8 ha = *(const short8*)(h_in + (rb + m) * 32 + q * 8);  // interleaved A-layout
        float tf[8];
        #pragma unroll
        for (int j = 0; j < 8; ++j)
            tf[j] = silu_f(a1k[j] * bf2f(((const unsigned short*)&ha)[j]) + c1k[j]);
        const short8 ta = pack8(tf);
        const f32x4 z = {0.f, 0.f, 0.f, 0.f};
        f32x4 r0 = mfma16(ta, W10, z);
        f32x4 r1 = mfma16(ta, W11, z);
        float uf0[4], uf1[4];
        #pragma unroll
        for (int r = 0; r < 4; ++r) {
            uf0[r] = silu_f(a2c0 * r0[r] + d2c0);
            uf1[r] = silu_f(a2c1 * r1[r] + d2c1);
        }
        // C-layout -> interleaved A-layout: 4x ds_write_b32 (pack+transpose merged), 4-way banks
        __builtin_amdgcn_wave_barrier();
        #pragma unroll
        for (int r = 0; r < 4; ++r)
            *(unsigned*)&myT[(q * 4 + r) * 32 + 2 * m] = cvt_pk_bf16(uf0[r], uf1[r]);
        __builtin_amdgcn_wave_barrier();
        const short8 ua = *(const short8*)(myT + m * 32 + q * 8);
        f32x4 c0 = {b2c0, b2c0, b2c0, b2c0}, c1 = {b2c1, b2c1, b2c1, b2c1};
        c0 = mfma16(ha, F0, c0);  c1 = mfma16(ha, F1, c1);
        c0 = mfma16(ua, W20, c0); c1 = mfma16(ua, W21, c1);
        float hn0[4], hn1[4];
        #pragma unroll
        for (int r = 0; r < 4; ++r) { hn0[r] = silu_f(c0[r]); hn1[r] = silu_f(c1[r]); }
        __builtin_amdgcn_wave_barrier();
        #pragma unroll
        for (int r = 0; r < 4; ++r)
            *(unsigned*)&myT[(q * 4 + r) * 32 + 2 * m] = cvt_pk_bf16(hn0[r], hn1[r]);
        __builtin_amdgcn_wave_barrier();
        if (!LAST) {
            #pragma unroll
            for (int r = 0; r < 4; ++r) {
                sS0 += hn0[r]; sQ0 += hn0[r] * hn0[r];
                sS1 += hn1[r]; sQ1 += hn1[r] * hn1[r];
            }
            const short8 hv = *(const short8*)(myT + lane * 8);
            *(short8*)(h_out + rb * 32 + lane * 8) = hv;
        } else {
            // head via MFMA: hn (interleaved A-layout from tile) @ head_w[chan-permuted K] + head_b
            const short8 hna = *(const short8*)(myT + m * 32 + q * 8);
            f32x4 oc = {hbc, hbc, hbc, hbc};
            oc = mfma16(hna, HW, oc);
            if (m < 10) {
                #pragma unroll
                for (int r = 0; r < 4; ++r) out[(rb + q * 4 + r) * 10 + m] = oc[r];
            }
        }
        __builtin_amdgcn_wave_barrier();
    }
    if (!LAST)
        stats_reduce_c(sS0, sQ0, sS1, sQ1, sRed, sOut + (size_t)(blockIdx.x & (NREP - 1)) * 64, tid);
}

extern "C" void kernel_launch(void* const* d_in, const int* in_sizes, int n_in,
                              void* d_out, int out_size, void* d_ws, size_t ws_size,
                              hipStream_t stream)
{
    const float* x      = (const float*)d_in[0];
    const float* stem_w = (const float*)d_in[1];
    const float* stem_b = (const float*)d_in[2];
    const float* fno_wr = (const float*)d_in[3];
    const float* fno_wi = (const float*)d_in[4];
    const float* bn1_g  = (const float*)d_in[5];
    const float* bn1_b  = (const float*)d_in[6];
    const float* lin1_w = (const float*)d_in[7];
    const float* lin1_b = (const float*)d_in[8];
    const float* bn2_g  = (const float*)d_in[9];
    const float* bn2_b  = (const float*)d_in[10];
    const float* lin2_w = (const float*)d_in[11];
    const float* lin2_b = (const float*)d_in[12];
    const float* head_w = (const float*)d_in[13];
    const float* head_b = (const float*)d_in[14];

    // workspace: [ h (B*32 bf16, 128 MiB) | Fp (4*1024 f32) | stats (8 sets * 16 reps * 64 f64) ]
    ushort_t* h  = (ushort_t*)d_ws;
    float*    Fp = (float*)((char*)d_ws + (size_t)BATCH * 32 * sizeof(ushort_t));
    double*   st = (double*)((char*)d_ws + (size_t)BATCH * 32 * sizeof(ushort_t) + 16384);

    hipMemsetAsync(st, 0, (size_t)NSETS * NREP * 64 * sizeof(double), stream);
    setup_f_kernel<<<4, BLOCK, 0, stream>>>(fno_wr, fno_wi, Fp);
    stem_kernel<<<GRID, BLOCK, 0, stream>>>(x, stem_w, stem_b, h, st);

    for (int l = 0; l < 4; ++l) {
        double* sH = st + (size_t)(2 * l) * NREP * 64;
        double* sR = st + (size_t)(2 * l + 1) * NREP * 64;
        p1_kernel<<<GRID, BLOCK, 0, stream>>>(
            h, sH, sR,
            bn1_g + l * 32, bn1_b + l * 32, lin1_w + l * 1024, lin1_b + l * 32);
        if (l < 3) {
            double* sN = st + (size_t)(2 * l + 2) * NREP * 64;
            p2_kernel<false><<<GRID, BLOCK, 0, stream>>>(
                h, h, nullptr, sH, sR, sN,
                bn1_g + l * 32, bn1_b + l * 32, lin1_w + l * 1024, lin1_b + l * 32,
                bn2_g + l * 32, bn2_b + l * 32, lin2_w + l * 1024, lin2_b + l * 32,
                Fp + l * 1024, nullptr, nullptr);
        } else {
            p2_kernel<true><<<GRID, BLOCK, 0, stream>>>(
                h, nullptr, (float*)d_out, sH, sR, st,
                bn1_g + l * 32, bn1_b + l * 32, lin1_w + l * 1024, lin1_b + l * 32,
                bn2_g + l * 32, bn2_b + l * 32, lin2_w + l * 1024, lin2_b + l * 32,
                Fp + l * 1024, head_w, head_b);
        }
    }
}